// Round 17
// baseline (153.033 us; speedup 1.0000x reference)
//
#include <hip/hip_runtime.h>
#include <cstdint>
#include <cstddef>

typedef __bf16 bf16;
typedef __bf16 bf16x4 __attribute__((ext_vector_type(4)));
typedef __bf16 bf16x8 __attribute__((ext_vector_type(8)));
typedef float f32x4 __attribute__((ext_vector_type(4)));
typedef float f32x16 __attribute__((ext_vector_type(16)));

typedef const __attribute__((address_space(1))) void* gas_ptr;
typedef __attribute__((address_space(3))) void* las_ptr;

#define GLOAD_LDS16(g, l) __builtin_amdgcn_global_load_lds((gas_ptr)(g), (las_ptr)(l), 16, 0, 0)

// ---------------- f32 -> bf16 convert (vectorized, grid-stride) ----------------
__global__ void cvt_f32_bf16(const float* __restrict__ in, bf16* __restrict__ out, int n4) {
  int i = blockIdx.x * blockDim.x + threadIdx.x;
  int stride = gridDim.x * blockDim.x;
  for (; i < n4; i += stride) {
    float4 v = reinterpret_cast<const float4*>(in)[i];
    bf16x4 o;
    o[0] = (bf16)v.x; o[1] = (bf16)v.y; o[2] = (bf16)v.z; o[3] = (bf16)v.w;
    reinterpret_cast<bf16x4*>(out)[i] = o;
  }
}

// ---------------- GEMM: C[M,N] = A[M,K] * B[N,K]^T  (m97-clone, high TLP) -----
// r17: r10-r16 all moved staged bytes at 5-9 B/cy/CU; m97 (identical drain
// structure!) achieves ~46 B/cy/CU. The difference is TRUE multi-block
// co-residency: m97 = 256 threads + 16KB LDS -> 3+ blocks/CU; our 512-thread
// / 48-128KB blocks measured ~1 block/CU every round. attn (256thr, 32KB,
// 3 blocks/CU) is the one kernel that hit target -- same pattern.
// So: 128x128 tile, BK=32, 4 waves, SINGLE 16KB buffer, plain drain
// (stage -> vmcnt0+sync -> 16 MFMA -> sync), VGPR ~68, (256,4) ->
// up to 8 blocks/CU (wave-capped). Cross-block TLP hides the drain.
// Fragment-order LDS (lane-linear, 0 conflicts) + XCD row-chunk swizzle kept.
template <int MODE>
__global__ __launch_bounds__(256, 4) void gemm_bt(
    const bf16* __restrict__ A, const bf16* __restrict__ B,
    int M, int N, int K,
    bf16* __restrict__ outb, float* __restrict__ outf,
    const float* __restrict__ bias) {
  constexpr int BK = 32;
  __shared__ bf16 ldsA[4096];    // 8 slots x 512 elems (16 rows x 32k each)
  __shared__ bf16 ldsB[4096];
  const int tid = threadIdx.x;
  const int l = tid & 63;
  const int w = tid >> 6;        // 0..3
  const int wr = w >> 1, wc = w & 1;
  const int lr = l & 15, lg = l >> 4;

  // XCD row-chunk swizzle: gx=64 row-tiles, 8 per XCD; col-major in chunk.
  const int bid = blockIdx.y * gridDim.x + blockIdx.x;
  const int xcd = bid & 7, c = bid >> 3;
  const int brow = (xcd * 8 + (c & 7)) * 128;
  const int bcol = (c >> 3) * 128;

  // staging: wave w stages A slots {w, 4+w} and B slots {w, 4+w}
  const bf16* sa0 = A + (size_t)(brow + w * 16 + lr) * K + lg * 8;
  const bf16* sa1 = sa0 + (size_t)64 * K;
  const bf16* sb0 = B + (size_t)(bcol + w * 16 + lr) * K + lg * 8;
  const bf16* sb1 = sb0 + (size_t)64 * K;
  const int d0 = w * 512 + l * 8;
  const int d1 = (4 + w) * 512 + l * 8;

  f32x4 acc[4][4] = {};

  for (int k0 = 0; k0 < K; k0 += BK) {
    GLOAD_LDS16(sa0 + k0, &ldsA[d0]);
    GLOAD_LDS16(sa1 + k0, &ldsA[d1]);
    GLOAD_LDS16(sb0 + k0, &ldsB[d0]);
    GLOAD_LDS16(sb1 + k0, &ldsB[d1]);
    asm volatile("s_waitcnt vmcnt(0)" ::: "memory");
    __syncthreads();

    bf16x8 af[4], bfr[4];
#pragma unroll
    for (int mi = 0; mi < 4; mi++)
      af[mi] = *reinterpret_cast<const bf16x8*>(&ldsA[(wr * 4 + mi) * 512 + l * 8]);
#pragma unroll
    for (int ni = 0; ni < 4; ni++)
      bfr[ni] = *reinterpret_cast<const bf16x8*>(&ldsB[(wc * 4 + ni) * 512 + l * 8]);
#pragma unroll
    for (int mi = 0; mi < 4; mi++)
#pragma unroll
      for (int ni = 0; ni < 4; ni++)
        acc[mi][ni] = __builtin_amdgcn_mfma_f32_16x16x32_bf16(af[mi], bfr[ni], acc[mi][ni], 0, 0, 0);
    __syncthreads();   // readers done before next stage overwrites
  }

  // epilogue: C frag mapping col = lr, row = lg*4 + r  (branch-free row-major)
#pragma unroll
  for (int mi = 0; mi < 4; mi++) {
#pragma unroll
    for (int r = 0; r < 4; r++) {
      const int m = brow + wr * 64 + mi * 16 + lg * 4 + r;
#pragma unroll
      for (int ni = 0; ni < 4; ni++) {
        const int e = bcol + wc * 64 + ni * 16 + lr;
        const float v = acc[mi][ni][r];
        if (MODE == 1) {
          outf[(size_t)m * N + e] = v + bias[e];
        } else {
          outb[(size_t)m * N + e] = (bf16)v;
        }
      }
    }
  }
}

// ---------------- V transpose: qkv cols [1536..2304) -> vtb[96][64][1024] -----
__global__ __launch_bounds__(256) void vtrans(const bf16* __restrict__ qkv,
                                              bf16* __restrict__ vtb) {
  __shared__ bf16 t[64 * 72];
  const int bh = blockIdx.x;          // 0..95
  const int b = bh / 12, h = bh % 12;
  const int nt = blockIdx.y;          // 0..15
  const int tid = threadIdx.x;
#pragma unroll
  for (int it = 0; it < 2; it++) {
    const int item = tid + it * 256;  // 0..511
    const int nl = item >> 3, c = item & 7;
    bf16x8 v = *reinterpret_cast<const bf16x8*>(
        &qkv[(size_t)(b * 1024 + nt * 64 + nl) * 2304 + 1536 + h * 64 + c * 8]);
#pragma unroll
    for (int j = 0; j < 8; j++) t[(c * 8 + j) * 72 + nl] = v[j];
  }
  __syncthreads();
#pragma unroll
  for (int it = 0; it < 2; it++) {
    const int item = tid + it * 256;
    const int d = item >> 3, c2 = item & 7;
    bf16x8 v = *reinterpret_cast<const bf16x8*>(&t[d * 72 + c2 * 8]);
    *reinterpret_cast<bf16x8*>(
        &vtb[(size_t)bh * 65536 + d * 1024 + nt * 64 + c2 * 8]) = v;
  }
}

// ---------------- Flash attention: LDS-staged, fragment-order layout ----------
// (unchanged from r9 -- this structure took attn 99.5 -> ~20 us)
__global__ __launch_bounds__(256, 3) void attn_kernel(
    const bf16* __restrict__ QKV, const bf16* __restrict__ Vt,
    bf16* __restrict__ Out) {
  __shared__ bf16 Kb[2][4096];   // 8KB per buffer, fragment-order
  __shared__ bf16 Vb[2][4096];
  const int tid = threadIdx.x;
  const int l = tid & 63;
  const int w = tid >> 6;
  const int ql = l & 31;
  const int hi = l >> 5;
  const int bh = blockIdx.x;       // 0..95 (head-major -> XCD pinning)
  const int b = bh / 12, h = bh % 12;
  const int q0 = blockIdx.y * 128 + w * 32;
  const bf16* Vh = Vt + (size_t)bh * 65536;
  constexpr float L2E = 1.4426950408889634f;

  const int kdst0 = (0 * 4 + w) * 512 + l * 8;
  const int kdst1 = (1 * 4 + w) * 512 + l * 8;
  const bf16* ksrc0 = QKV + (size_t)(b * 1024 + ql) * 2304 + 768 + h * 64 + w * 16 + hi * 8;
  const bf16* ksrc1 = ksrc0 + (size_t)32 * 2304;
  const bf16* vsrc0 = Vh + (size_t)((w & 1) * 32 + ql) * 1024 + ((0 * 4 + w) >> 1) * 16 + hi * 8;
  const bf16* vsrc1 = Vh + (size_t)((w & 1) * 32 + ql) * 1024 + ((1 * 4 + w) >> 1) * 16 + hi * 8;

  const bf16* Qrow = QKV + (size_t)(b * 1024 + q0 + ql) * 2304 + h * 64;
  bf16x8 qf[4];
#pragma unroll
  for (int s = 0; s < 4; s++)
    qf[s] = *reinterpret_cast<const bf16x8*>(&Qrow[s * 16 + hi * 8]);

  f32x16 o[2] = {};
  float ls0 = 0.f, ls1 = 0.f, ls2 = 0.f, ls3 = 0.f;

  GLOAD_LDS16(ksrc0, &Kb[0][kdst0]);
  GLOAD_LDS16(ksrc1, &Kb[0][kdst1]);
  GLOAD_LDS16(vsrc0, &Vb[0][kdst0]);
  GLOAD_LDS16(vsrc1, &Vb[0][kdst1]);
  asm volatile("s_waitcnt vmcnt(0)" ::: "memory");
  __syncthreads();

  int p = 0;
  for (int it = 0; it < 16; ++it) {
    const int kt = it * 64;
    if (it < 15) {
      GLOAD_LDS16(ksrc0 + (size_t)(kt + 64) * 2304, &Kb[p ^ 1][kdst0]);
      GLOAD_LDS16(ksrc1 + (size_t)(kt + 64) * 2304, &Kb[p ^ 1][kdst1]);
      GLOAD_LDS16(vsrc0 + (kt + 64), &Vb[p ^ 1][kdst0]);
      GLOAD_LDS16(vsrc1 + (kt + 64), &Vb[p ^ 1][kdst1]);
    }

    bf16x8 kf[8];
#pragma unroll
    for (int r = 0; r < 8; r++)
      kf[r] = *reinterpret_cast<const bf16x8*>(&Kb[p][r * 512 + l * 8]);
    f32x16 st0 = {}, st1 = {};
    __builtin_amdgcn_s_setprio(1);
#pragma unroll
    for (int s = 0; s < 4; s++) {
      st0 = __builtin_amdgcn_mfma_f32_32x32x16_bf16(kf[s], qf[s], st0, 0, 0, 0);
      st1 = __builtin_amdgcn_mfma_f32_32x32x16_bf16(kf[4 + s], qf[s], st1, 0, 0, 0);
    }
    __builtin_amdgcn_s_setprio(0);

#pragma unroll
    for (int r = 0; r < 16; r++) {
      float a0 = st0[r] * L2E, a1 = st1[r] * L2E;
      float e0, e1;
      asm("v_exp_f32 %0, %1" : "=v"(e0) : "v"(a0));
      asm("v_exp_f32 %0, %1" : "=v"(e1) : "v"(a1));
      st0[r] = e0; st1[r] = e1;
    }
#pragma unroll
    for (int r = 0; r < 16; r += 2) {
      ls0 += st0[r]; ls1 += st0[r + 1];
      ls2 += st1[r]; ls3 += st1[r + 1];
    }

    bf16x8 pfv[4];
#pragma unroll
    for (int t = 0; t < 4; t++) {
      const int c8 = (t & 1) * 8;
      const f32x16& sv = (t < 2) ? st0 : st1;
      uint32_t wA0, wA1, wB0, wB1;
      asm("v_cvt_pk_bf16_f32 %0, %1, %2" : "=v"(wA0) : "v"(sv[c8 + 0]), "v"(sv[c8 + 1]));
      asm("v_cvt_pk_bf16_f32 %0, %1, %2" : "=v"(wA1) : "v"(sv[c8 + 2]), "v"(sv[c8 + 3]));
      asm("v_cvt_pk_bf16_f32 %0, %1, %2" : "=v"(wB0) : "v"(sv[c8 + 4]), "v"(sv[c8 + 5]));
      asm("v_cvt_pk_bf16_f32 %0, %1, %2" : "=v"(wB1) : "v"(sv[c8 + 6]), "v"(sv[c8 + 7]));
      asm("v_permlane32_swap_b32 %0, %1" : "+v"(wA0), "+v"(wB0));
      asm("v_permlane32_swap_b32 %0, %1" : "+v"(wA1), "+v"(wB1));
      union { uint32_t u[4]; bf16x8 v; } pf;
      pf.u[0] = wA0; pf.u[1] = wA1; pf.u[2] = wB0; pf.u[3] = wB1;
      pfv[t] = pf.v;
    }

    bf16x8 vf[8];
#pragma unroll
    for (int r = 0; r < 8; r++)
      vf[r] = *reinterpret_cast<const bf16x8*>(&Vb[p][r * 512 + l * 8]);
    __builtin_amdgcn_s_setprio(1);
#pragma unroll
    for (int t = 0; t < 4; t++) {
      o[0] = __builtin_amdgcn_mfma_f32_32x32x16_bf16(vf[t * 2 + 0], pfv[t], o[0], 0, 0, 0);
      o[1] = __builtin_amdgcn_mfma_f32_32x32x16_bf16(vf[t * 2 + 1], pfv[t], o[1], 0, 0, 0);
    }
    __builtin_amdgcn_s_setprio(0);

    asm volatile("s_waitcnt vmcnt(0)" ::: "memory");
    __syncthreads();
    p ^= 1;
  }

  float lsum = (ls0 + ls1) + (ls2 + ls3);
  lsum += __shfl_xor(lsum, 32);
  const float rl = 1.0f / lsum;
  bf16* orow = Out + (size_t)(b * 1024 + q0 + ql) * 768 + h * 64;
#pragma unroll
  for (int dh = 0; dh < 2; dh++)
#pragma unroll
    for (int rq = 0; rq < 4; rq++) {
      union { ushort us[4]; uint2 v; } pk;
#pragma unroll
      for (int i = 0; i < 4; i++) {
        const bf16 hv = (bf16)(o[dh][rq * 4 + i] * rl);
        pk.us[i] = __builtin_bit_cast(ushort, hv);
      }
      *reinterpret_cast<uint2*>(&orow[dh * 32 + rq * 8 + hi * 4]) = pk.v;
    }
}

// ---------------- launch ------------------------------------------------------
extern "C" void kernel_launch(void* const* d_in, const int* in_sizes, int n_in,
                              void* d_out, int out_size, void* d_ws, size_t ws_size,
                              hipStream_t stream) {
  const float* x = (const float*)d_in[0];
  const float* w_qkv = (const float*)d_in[1];
  const float* w_fc = (const float*)d_in[2];
  const float* b_fc = (const float*)d_in[3];
  float* out = (float*)d_out;
  char* ws = (char*)d_ws;

  bf16* xb = (bf16*)(ws);                    // 8192x768   (dead after gemm<0>)
  bf16* vtb = (bf16*)(ws);                   // 96x64x1024 (aliases xb -- safe)
  bf16* wqkb = (bf16*)(ws + 12582912);       // 2304x768
  bf16* wfcb = (bf16*)(ws + 16121856);       // 768x768
  bf16* qkvb = (bf16*)(ws + 17301504);       // 8192x2304
  bf16* aob = (bf16*)(ws + 55050240);        // 8192x768

  cvt_f32_bf16<<<2048, 256, 0, stream>>>(x, xb, 6291456 / 4);
  cvt_f32_bf16<<<1728, 256, 0, stream>>>(w_qkv, wqkb, 1769472 / 4);
  cvt_f32_bf16<<<576, 256, 0, stream>>>(w_fc, wfcb, 589824 / 4);

  gemm_bt<0><<<dim3(64, 18), 256, 0, stream>>>(xb, wqkb, 8192, 2304, 768,
                                               qkvb, nullptr, nullptr);

  vtrans<<<dim3(96, 16), 256, 0, stream>>>(qkvb, vtb);

  attn_kernel<<<dim3(96, 8), 256, 0, stream>>>(qkvb, vtb, aob);

  gemm_bt<1><<<dim3(64, 6), 256, 0, stream>>>(aob, wfcb, 8192, 768, 768,
                                              nullptr, out, b_fc);
}